// Round 6
// baseline (541.905 us; speedup 1.0000x reference)
//
#include <hip/hip_runtime.h>
#include <hip/hip_bf16.h>
#include <stdint.h>

typedef __bf16 bf16;
typedef __attribute__((ext_vector_type(8))) __bf16 bf16x8;
typedef __attribute__((ext_vector_type(4))) float f32x4;

constexpr int S   = 2048;
constexpr int DH  = 64;
constexpr int BQ  = 16;          // q-rows per block
constexpr int NW  = 8;           // waves per block
constexpr int KPW = S / NW;      // 256 keys per wave
constexpr int NC  = KPW / 32;    // 8 chunks of 32 keys

// Fragment conventions (verified rounds 1-5):
//   mfma(X, Y, acc): X lane(c,g) = X[i=c][k=g*8+j]; Y lane(c,g) = Y[j2=c][k=g*8+j]
//   D lane(c,g) reg r = D[i=g*4+r][j2=c]
// Swapped QK^T mfma(Kfrag, Qfrag) with K-row permutation perm(i)=8*(i>>2)+(i&3):
//   acc0 loads K[k0+perm(c)],   acc1 loads K[k0+perm(c)+4]
//   -> lane(c,g): acc0 reg r = P[key=k0+8g+r][q=c], acc1 reg r = P[key=k0+8g+4+r][q=c]
//   -> lane owns 8 CONTIGUOUS keys k0+8g..k0+8g+7 of q-row c (32B W store, 1-base V reads)
//
// NOTE on __launch_bounds__: empirically (rounds 1-5) the 2nd arg CAPS waves/EU
// on this toolchain (occupancy == 4*arg waves/CU every round). Use 6:
// VGPR cap 512/6=85 (kernel needs ~76), residency 24 waves/CU (3 blocks).

__global__ __launch_bounds__(512, 6)
void attn_fused(const float* __restrict__ Q, const float* __restrict__ K,
                const float* __restrict__ V, const float* __restrict__ Msk,
                float* __restrict__ Out, float* __restrict__ W)
{
    __shared__ float rs[NW][BQ];          // per-wave row-sum partials
    __shared__ float inv[BQ];             // 1/rowsum
    __shared__ float opart[NW][BQ][DH];   // per-wave O partials (32 KB)

    const int tid  = threadIdx.x;
    const int lane = tid & 63;
    const int wave = tid >> 6;            // 0..7
    const int c    = lane & 15;
    const int g    = lane >> 4;           // 0..3

    // XCD-aware swizzle: each XCD gets 512 consecutive swz -> 4 contiguous bh
    const int swz = (blockIdx.x & 7) * 512 + (blockIdx.x >> 3);
    const int bh = swz >> 7;              // 0..31
    const int q0 = (swz & 127) * BQ;

    const float* Qb = Q + (size_t)bh * S * DH;
    const float* Kb = K + (size_t)bh * S * DH;
    const float* Vb = V + (size_t)bh * S * DH;

    // ---- Q fragment (Y-operand): lane(c,g) = Q[q0+c][g*8+j], dh halves lo/hi
    bf16x8 qlo, qhi;
    {
        const float* qr = Qb + (size_t)(q0 + c) * DH + g * 8;
        f32x4 a0 = *(const f32x4*)(qr);
        f32x4 a1 = *(const f32x4*)(qr + 4);
        f32x4 b0 = *(const f32x4*)(qr + 32);
        f32x4 b1 = *(const f32x4*)(qr + 36);
        #pragma unroll
        for (int j = 0; j < 4; ++j) {
            qlo[j]     = (bf16)a0[j];  qlo[j + 4] = (bf16)a1[j];
            qhi[j]     = (bf16)b0[j];  qhi[j + 4] = (bf16)b1[j];
        }
    }

    const int kbase = wave * KPW;                     // wave owns 256 keys
    const int cperm = 8 * (c >> 2) + (c & 3);         // K-row permutation
    const float* mrow = Msk + (size_t)(q0 + c) * S;   // this lane's q-row of the mask

    // =========== Loop 1: QK^T -> exp -> pa regs + row sums (K read once) ===========
    bf16x8 pa[NC];
    float s = 0.f;
    #pragma unroll
    for (int kc = 0; kc < NC; ++kc) {
        const int k0 = kbase + kc * 32;
        const float* kr0 = Kb + (size_t)(k0 + cperm) * DH + g * 8;   // keys k0+perm(c)
        const float* kr1 = kr0 + (size_t)4 * DH;                     // keys k0+perm(c)+4
        f32x4 a0 = *(const f32x4*)(kr0);
        f32x4 a1 = *(const f32x4*)(kr0 + 4);
        f32x4 b0 = *(const f32x4*)(kr0 + 32);
        f32x4 b1 = *(const f32x4*)(kr0 + 36);
        f32x4 a2 = *(const f32x4*)(kr1);
        f32x4 a3 = *(const f32x4*)(kr1 + 4);
        f32x4 b2 = *(const f32x4*)(kr1 + 32);
        f32x4 b3 = *(const f32x4*)(kr1 + 36);
        f32x4 m0 = *(const f32x4*)(mrow + k0 + 8 * g);       // keys k0+8g..+3
        f32x4 m1 = *(const f32x4*)(mrow + k0 + 8 * g + 4);   // keys k0+8g+4..+7

        bf16x8 kl0, kh0, kl1, kh1;
        #pragma unroll
        for (int j = 0; j < 4; ++j) {
            kl0[j] = (bf16)a0[j];  kl0[j + 4] = (bf16)a1[j];
            kh0[j] = (bf16)b0[j];  kh0[j + 4] = (bf16)b1[j];
            kl1[j] = (bf16)a2[j];  kl1[j + 4] = (bf16)a3[j];
            kh1[j] = (bf16)b2[j];  kh1[j + 4] = (bf16)b3[j];
        }
        f32x4 acc0 = {0.f, 0.f, 0.f, 0.f};
        f32x4 acc1 = {0.f, 0.f, 0.f, 0.f};
        acc0 = __builtin_amdgcn_mfma_f32_16x16x32_bf16(kl0, qlo, acc0, 0, 0, 0);
        acc0 = __builtin_amdgcn_mfma_f32_16x16x32_bf16(kh0, qhi, acc0, 0, 0, 0);
        acc1 = __builtin_amdgcn_mfma_f32_16x16x32_bf16(kl1, qlo, acc1, 0, 0, 0);
        acc1 = __builtin_amdgcn_mfma_f32_16x16x32_bf16(kh1, qhi, acc1, 0, 0, 0);

        #pragma unroll
        for (int r = 0; r < 4; ++r) {
            const float p0 = __expf(acc0[r] * 0.125f + m0[r] * (-1e9f));
            const float p1 = __expf(acc1[r] * 0.125f + m1[r] * (-1e9f));
            s += p0 + p1;
            pa[kc][r]     = (bf16)p0;   // key k0+8g+r
            pa[kc][r + 4] = (bf16)p1;   // key k0+8g+4+r
        }
    }

    // reduce over g-groups (same q=c), then across waves
    s += __shfl_xor(s, 16);
    s += __shfl_xor(s, 32);
    if (lane < 16) rs[wave][lane] = s;
    __syncthreads();
    if (tid < BQ) {
        float t = 0.f;
        #pragma unroll
        for (int w = 0; w < NW; ++w) t += rs[w][tid];
        inv[tid] = 1.f / t;
    }
    __syncthreads();
    const float myinv = inv[c];

    // =========== Loop 2: W write (normalized f32, 32B/lane contiguous) + PV ===========
    f32x4 oacc[4] = {{0,0,0,0},{0,0,0,0},{0,0,0,0},{0,0,0,0}};
    float* Wrow = W + (size_t)bh * S * S + (size_t)(q0 + c) * S;

    #pragma unroll
    for (int kc = 0; kc < NC; ++kc) {
        const int k0 = kbase + kc * 32;

        // --- V loads first (independent; overlap with stores): rows k0+8g+j, cols c+16dt
        const float* vp = Vb + (size_t)(k0 + 8 * g) * DH + c;
        float vv[4][8];
        #pragma unroll
        for (int j = 0; j < 8; ++j) {
            #pragma unroll
            for (int dt = 0; dt < 4; ++dt)
                vv[dt][j] = vp[j * DH + dt * 16];
        }

        // --- W write straight from pa regs: keys k0+8g..k0+8g+7 (32B contiguous)
        f32x4 w0, w1;
        #pragma unroll
        for (int r = 0; r < 4; ++r) {
            w0[r] = (float)pa[kc][r]     * myinv;
            w1[r] = (float)pa[kc][r + 4] * myinv;
        }
        *(f32x4*)(Wrow + k0 + 8 * g)     = w0;
        *(f32x4*)(Wrow + k0 + 8 * g + 4) = w1;

        // --- PV: vb slot (g,j) = V[key=k0+8g+j][d=c+16dt] matches pa slot keys
        #pragma unroll
        for (int dt = 0; dt < 4; ++dt) {
            bf16x8 vb;
            #pragma unroll
            for (int j = 0; j < 8; ++j) vb[j] = (bf16)vv[dt][j];
            oacc[dt] = __builtin_amdgcn_mfma_f32_16x16x32_bf16(pa[kc], vb, oacc[dt], 0, 0, 0);
        }
    }

    // --- cross-wave O reduction: lane(c,g) reg r of oacc[dt] = O[q=4g+r][d=16dt+c]
    #pragma unroll
    for (int dt = 0; dt < 4; ++dt)
        #pragma unroll
        for (int r = 0; r < 4; ++r)
            opart[wave][4 * g + r][16 * dt + c] = oacc[dt][r];
    __syncthreads();

    if (tid < BQ * 16) {
        const int q = tid >> 4;            // 0..15
        const int d = (tid & 15) * 4;      // 0..60
        f32x4 o = {0.f, 0.f, 0.f, 0.f};
        #pragma unroll
        for (int w = 0; w < NW; ++w) o += *(const f32x4*)&opart[w][q][d];
        const float is = inv[q];
        o.x *= is; o.y *= is; o.z *= is; o.w *= is;
        float* Ob = Out + ((size_t)bh * S + q0 + q) * DH + d;
        *(f32x4*)Ob = o;
    }
}

extern "C" void kernel_launch(void* const* d_in, const int* in_sizes, int n_in,
                              void* d_out, int out_size, void* d_ws, size_t ws_size,
                              hipStream_t stream) {
    const float* Q   = (const float*)d_in[0];
    const float* K   = (const float*)d_in[1];
    const float* V   = (const float*)d_in[2];
    const float* Msk = (const float*)d_in[3];

    float* Out = (float*)d_out;                       // [2,16,2048,64]
    float* W   = Out + (size_t)2 * 16 * 2048 * 64;    // [2,16,2048,2048]

    dim3 grid(32 * (S / BQ));
    dim3 block(512);
    hipLaunchKernelGGL(attn_fused, grid, block, 0, stream, Q, K, V, Msk, Out, W);
}

// Round 7
// 512.799 us; speedup vs baseline: 1.0568x; 1.0568x over previous
//
#include <hip/hip_runtime.h>
#include <hip/hip_bf16.h>
#include <stdint.h>

typedef __bf16 bf16;
typedef __attribute__((ext_vector_type(8))) __bf16 bf16x8;
typedef __attribute__((ext_vector_type(4))) float f32x4;

constexpr int S   = 2048;
constexpr int DH  = 64;
constexpr int BQ  = 16;          // q-rows per block
constexpr int NW  = 8;           // waves per block
constexpr int KPW = S / NW;      // 256 keys per wave
constexpr int NC  = KPW / 32;    // 8 chunks of 32 keys

// Fragment conventions (verified rounds 1-5):
//   mfma(X, Y, acc): X lane(c,g) = X[i=c][k=g*8+j]; Y lane(c,g) = Y[j2=c][k=g*8+j]
//   D lane(c,g) reg r = D[i=g*4+r][j2=c]
// Swapped QK^T mfma(Kfrag, Qfrag) with K-row permutation perm(i)=8*(i>>2)+(i&3):
//   acc0 loads K[k0+perm(c)],   acc1 loads K[k0+perm(c)+4]
//   -> lane(c,g): acc0 reg r = P[key=k0+8g+r][q=c], acc1 reg r = P[key=k0+8g+4+r][q=c]
//   -> lane owns 8 CONTIGUOUS keys k0+8g..k0+8g+7 of q-row c (32B W store, 1-base V reads)
//
// __launch_bounds__ 2nd arg empirically pins occupancy at 4*arg waves/CU
// (rounds 1-6) AND sets VGPR budget = 2048/(4*arg). Kernel needs ~88 regs:
//   arg=6 -> budget 85 -> SPILLS (r6: +372MB scratch writes). arg=5 -> budget
//   ~102, 20 waves/CU (62%) -> best no-spill occupancy.

__global__ __launch_bounds__(512, 5)
void attn_fused(const float* __restrict__ Q, const float* __restrict__ K,
                const float* __restrict__ V, const float* __restrict__ Msk,
                float* __restrict__ Out, float* __restrict__ W)
{
    __shared__ float rs[NW][BQ];          // per-wave row-sum partials
    __shared__ float inv[BQ];             // 1/rowsum
    __shared__ float opart[NW][BQ][DH];   // per-wave O partials (32 KB)

    const int tid  = threadIdx.x;
    const int lane = tid & 63;
    const int wave = tid >> 6;            // 0..7
    const int c    = lane & 15;
    const int g    = lane >> 4;           // 0..3

    // XCD-aware swizzle: each XCD gets 512 consecutive swz -> 4 contiguous bh
    const int swz = (blockIdx.x & 7) * 512 + (blockIdx.x >> 3);
    const int bh = swz >> 7;              // 0..31
    const int q0 = (swz & 127) * BQ;

    const float* Qb = Q + (size_t)bh * S * DH;
    const float* Kb = K + (size_t)bh * S * DH;
    const float* Vb = V + (size_t)bh * S * DH;

    // ---- Q fragment (Y-operand): lane(c,g) = Q[q0+c][g*8+j], dh halves lo/hi
    bf16x8 qlo, qhi;
    {
        const float* qr = Qb + (size_t)(q0 + c) * DH + g * 8;
        f32x4 a0 = *(const f32x4*)(qr);
        f32x4 a1 = *(const f32x4*)(qr + 4);
        f32x4 b0 = *(const f32x4*)(qr + 32);
        f32x4 b1 = *(const f32x4*)(qr + 36);
        #pragma unroll
        for (int j = 0; j < 4; ++j) {
            qlo[j]     = (bf16)a0[j];  qlo[j + 4] = (bf16)a1[j];
            qhi[j]     = (bf16)b0[j];  qhi[j + 4] = (bf16)b1[j];
        }
    }

    const int kbase = wave * KPW;                     // wave owns 256 keys
    const int cperm = 8 * (c >> 2) + (c & 3);         // K-row permutation
    const float* mrow = Msk + (size_t)(q0 + c) * S;   // this lane's q-row of the mask

    // =========== Loop 1: QK^T -> exp -> pa regs + row sums (K read once) ===========
    bf16x8 pa[NC];
    float s = 0.f;
    #pragma unroll
    for (int kc = 0; kc < NC; ++kc) {
        const int k0 = kbase + kc * 32;
        const float* kr0 = Kb + (size_t)(k0 + cperm) * DH + g * 8;   // keys k0+perm(c)
        const float* kr1 = kr0 + (size_t)4 * DH;                     // keys k0+perm(c)+4
        f32x4 a0 = *(const f32x4*)(kr0);
        f32x4 a1 = *(const f32x4*)(kr0 + 4);
        f32x4 b0 = *(const f32x4*)(kr0 + 32);
        f32x4 b1 = *(const f32x4*)(kr0 + 36);
        f32x4 a2 = *(const f32x4*)(kr1);
        f32x4 a3 = *(const f32x4*)(kr1 + 4);
        f32x4 b2 = *(const f32x4*)(kr1 + 32);
        f32x4 b3 = *(const f32x4*)(kr1 + 36);
        f32x4 m0 = *(const f32x4*)(mrow + k0 + 8 * g);       // keys k0+8g..+3
        f32x4 m1 = *(const f32x4*)(mrow + k0 + 8 * g + 4);   // keys k0+8g+4..+7

        bf16x8 kl0, kh0, kl1, kh1;
        #pragma unroll
        for (int j = 0; j < 4; ++j) {
            kl0[j] = (bf16)a0[j];  kl0[j + 4] = (bf16)a1[j];
            kh0[j] = (bf16)b0[j];  kh0[j + 4] = (bf16)b1[j];
            kl1[j] = (bf16)a2[j];  kl1[j + 4] = (bf16)a3[j];
            kh1[j] = (bf16)b2[j];  kh1[j + 4] = (bf16)b3[j];
        }
        f32x4 acc0 = {0.f, 0.f, 0.f, 0.f};
        f32x4 acc1 = {0.f, 0.f, 0.f, 0.f};
        acc0 = __builtin_amdgcn_mfma_f32_16x16x32_bf16(kl0, qlo, acc0, 0, 0, 0);
        acc0 = __builtin_amdgcn_mfma_f32_16x16x32_bf16(kh0, qhi, acc0, 0, 0, 0);
        acc1 = __builtin_amdgcn_mfma_f32_16x16x32_bf16(kl1, qlo, acc1, 0, 0, 0);
        acc1 = __builtin_amdgcn_mfma_f32_16x16x32_bf16(kh1, qhi, acc1, 0, 0, 0);

        #pragma unroll
        for (int r = 0; r < 4; ++r) {
            const float p0 = __expf(acc0[r] * 0.125f + m0[r] * (-1e9f));
            const float p1 = __expf(acc1[r] * 0.125f + m1[r] * (-1e9f));
            s += p0 + p1;
            pa[kc][r]     = (bf16)p0;   // key k0+8g+r
            pa[kc][r + 4] = (bf16)p1;   // key k0+8g+4+r
        }
    }

    // reduce over g-groups (same q=c), then across waves
    s += __shfl_xor(s, 16);
    s += __shfl_xor(s, 32);
    if (lane < 16) rs[wave][lane] = s;
    __syncthreads();
    if (tid < BQ) {
        float t = 0.f;
        #pragma unroll
        for (int w = 0; w < NW; ++w) t += rs[w][tid];
        inv[tid] = 1.f / t;
    }
    __syncthreads();
    const float myinv = inv[c];

    // =========== Loop 2: W write (normalized f32, 32B/lane contiguous) + PV ===========
    f32x4 oacc[4] = {{0,0,0,0},{0,0,0,0},{0,0,0,0},{0,0,0,0}};
    float* Wrow = W + (size_t)bh * S * S + (size_t)(q0 + c) * S;

    #pragma unroll
    for (int kc = 0; kc < NC; ++kc) {
        const int k0 = kbase + kc * 32;

        // --- V loads first (independent; overlap with stores): rows k0+8g+j, cols c+16dt
        const float* vp = Vb + (size_t)(k0 + 8 * g) * DH + c;
        float vv[4][8];
        #pragma unroll
        for (int j = 0; j < 8; ++j) {
            #pragma unroll
            for (int dt = 0; dt < 4; ++dt)
                vv[dt][j] = vp[j * DH + dt * 16];
        }

        // --- W write straight from pa regs: keys k0+8g..k0+8g+7 (32B contiguous)
        f32x4 w0, w1;
        #pragma unroll
        for (int r = 0; r < 4; ++r) {
            w0[r] = (float)pa[kc][r]     * myinv;
            w1[r] = (float)pa[kc][r + 4] * myinv;
        }
        *(f32x4*)(Wrow + k0 + 8 * g)     = w0;
        *(f32x4*)(Wrow + k0 + 8 * g + 4) = w1;

        // --- PV: vb slot (g,j) = V[key=k0+8g+j][d=c+16dt] matches pa slot keys
        #pragma unroll
        for (int dt = 0; dt < 4; ++dt) {
            bf16x8 vb;
            #pragma unroll
            for (int j = 0; j < 8; ++j) vb[j] = (bf16)vv[dt][j];
            oacc[dt] = __builtin_amdgcn_mfma_f32_16x16x32_bf16(pa[kc], vb, oacc[dt], 0, 0, 0);
        }
    }

    // --- cross-wave O reduction: lane(c,g) reg r of oacc[dt] = O[q=4g+r][d=16dt+c]
    #pragma unroll
    for (int dt = 0; dt < 4; ++dt)
        #pragma unroll
        for (int r = 0; r < 4; ++r)
            opart[wave][4 * g + r][16 * dt + c] = oacc[dt][r];
    __syncthreads();

    if (tid < BQ * 16) {
        const int q = tid >> 4;            // 0..15
        const int d = (tid & 15) * 4;      // 0..60
        f32x4 o = {0.f, 0.f, 0.f, 0.f};
        #pragma unroll
        for (int w = 0; w < NW; ++w) o += *(const f32x4*)&opart[w][q][d];
        const float is = inv[q];
        o.x *= is; o.y *= is; o.z *= is; o.w *= is;
        float* Ob = Out + ((size_t)bh * S + q0 + q) * DH + d;
        *(f32x4*)Ob = o;
    }
}

extern "C" void kernel_launch(void* const* d_in, const int* in_sizes, int n_in,
                              void* d_out, int out_size, void* d_ws, size_t ws_size,
                              hipStream_t stream) {
    const float* Q   = (const float*)d_in[0];
    const float* K   = (const float*)d_in[1];
    const float* V   = (const float*)d_in[2];
    const float* Msk = (const float*)d_in[3];

    float* Out = (float*)d_out;                       // [2,16,2048,64]
    float* W   = Out + (size_t)2 * 16 * 2048 * 64;    // [2,16,2048,2048]

    dim3 grid(32 * (S / BQ));
    dim3 block(512);
    hipLaunchKernelGGL(attn_fused, grid, block, 0, stream, Q, K, V, Msk, Out, W);
}

// Round 8
// 396.126 us; speedup vs baseline: 1.3680x; 1.2945x over previous
//
#include <hip/hip_runtime.h>
#include <hip/hip_bf16.h>
#include <stdint.h>

typedef __bf16 bf16;
typedef __attribute__((ext_vector_type(8))) __bf16 bf16x8;
typedef __attribute__((ext_vector_type(4))) float f32x4;

constexpr int S   = 2048;
constexpr int DH  = 64;
constexpr int BQ  = 16;          // q-rows per block
constexpr int LDP = S + 8;       // padded LDS row stride (bf16 elems)

// Best-known base = round-2 kernel (409 us, VGPR 88, no spill, WRITE 540.7 MB).
// Single change this round: phase-3 W stores are nontemporal. Phase 3 writes
// are thread-contiguous (each wave instruction covers 2 KB of FULL cache
// lines), so NT cannot cause partial-sector write inflation (r3's mistake was
// NT on scattered 16B pieces). Goal: stop the 537 MB W stream from churning
// L2/L3 so mask/K/V re-reads stay cache-resident (FETCH 332 -> ~120 MB).

__global__ __launch_bounds__(256, 2)
void attn_fused(const float* __restrict__ Q, const float* __restrict__ K,
                const float* __restrict__ V, const float* __restrict__ Msk,
                float* __restrict__ Out, float* __restrict__ W)
{
    __shared__ bf16  P[BQ][LDP];     // exp(logit) values (unnormalized), bf16
    __shared__ float rs[4][BQ];      // per-wave row sums
    __shared__ float inv[BQ];        // 1/rowsum

    const int tid  = threadIdx.x;
    const int lane = tid & 63;
    const int wave = tid >> 6;       // 0..3
    const int c    = lane & 15;      // fragment col
    const int g    = lane >> 4;      // fragment k-group 0..3

    // XCD-aware swizzle: XCD x gets swz in [x*512,(x+1)*512) -> 4 contiguous bh
    const int swz = (blockIdx.x & 7) * 512 + (blockIdx.x >> 3);
    const int bh = swz >> 7;                 // 0..31  (b*H+h)
    const int q0 = (swz & 127) * BQ;         // q-tile base

    const float* Qb = Q + (size_t)bh * S * DH;
    const float* Kb = K + (size_t)bh * S * DH;
    const float* Vb = V + (size_t)bh * S * DH;

    // ---- Q fragments (row = c, k = g*8+j / 32+g*8+j)
    bf16x8 qlo, qhi;
    {
        const float* qr = Qb + (size_t)(q0 + c) * DH + g * 8;
        f32x4 a0 = *(const f32x4*)(qr);
        f32x4 a1 = *(const f32x4*)(qr + 4);
        f32x4 b0 = *(const f32x4*)(qr + 32);
        f32x4 b1 = *(const f32x4*)(qr + 36);
        #pragma unroll
        for (int j = 0; j < 4; ++j) {
            qlo[j]     = (bf16)a0[j];  qlo[j + 4] = (bf16)a1[j];
            qhi[j]     = (bf16)b0[j];  qhi[j + 4] = (bf16)b1[j];
        }
    }

    // ---- Phase 1: QK^T -> exp(logit) in LDS (max-free softmax, data-bounded logits)
    float sums[4] = {0.f, 0.f, 0.f, 0.f};
    for (int i = 0; i < 16; ++i) {
        const int k0 = (wave * 2 + i * 8) * 16;       // keys [k0, k0+32)
        // --- issue all global loads first (8x f32x4 K + 8 mask scalars)
        const float* kr0 = Kb + (size_t)(k0 + c) * DH + g * 8;
        const float* kr1 = kr0 + (size_t)16 * DH;
        f32x4 a0 = *(const f32x4*)(kr0);
        f32x4 a1 = *(const f32x4*)(kr0 + 4);
        f32x4 b0 = *(const f32x4*)(kr0 + 32);
        f32x4 b1 = *(const f32x4*)(kr0 + 36);
        f32x4 a2 = *(const f32x4*)(kr1);
        f32x4 a3 = *(const f32x4*)(kr1 + 4);
        f32x4 b2 = *(const f32x4*)(kr1 + 32);
        f32x4 b3 = *(const f32x4*)(kr1 + 36);
        const float* mrow = Msk + (size_t)(q0 + g * 4) * S + k0 + c;
        float m0 = mrow[0], m1 = mrow[S], m2 = mrow[2 * S], m3 = mrow[3 * S];
        float n0 = mrow[16], n1 = mrow[S + 16], n2 = mrow[2 * S + 16], n3 = mrow[3 * S + 16];

        bf16x8 kl0, kh0, kl1, kh1;
        #pragma unroll
        for (int j = 0; j < 4; ++j) {
            kl0[j] = (bf16)a0[j];  kl0[j + 4] = (bf16)a1[j];
            kh0[j] = (bf16)b0[j];  kh0[j + 4] = (bf16)b1[j];
            kl1[j] = (bf16)a2[j];  kl1[j + 4] = (bf16)a3[j];
            kh1[j] = (bf16)b2[j];  kh1[j + 4] = (bf16)b3[j];
        }
        f32x4 acc0 = {0.f, 0.f, 0.f, 0.f};
        f32x4 acc1 = {0.f, 0.f, 0.f, 0.f};
        acc0 = __builtin_amdgcn_mfma_f32_16x16x32_bf16(qlo, kl0, acc0, 0, 0, 0);
        acc0 = __builtin_amdgcn_mfma_f32_16x16x32_bf16(qhi, kh0, acc0, 0, 0, 0);
        acc1 = __builtin_amdgcn_mfma_f32_16x16x32_bf16(qlo, kl1, acc1, 0, 0, 0);
        acc1 = __builtin_amdgcn_mfma_f32_16x16x32_bf16(qhi, kh1, acc1, 0, 0, 0);

        const float mk[4] = {m0, m1, m2, m3};
        const float nk[4] = {n0, n1, n2, n3};
        #pragma unroll
        for (int r = 0; r < 4; ++r) {
            const int row = g * 4 + r;                 // C/D: row=(lane>>4)*4+r
            const float p0 = __expf(acc0[r] * 0.125f + mk[r] * (-1e9f));
            const float p1 = __expf(acc1[r] * 0.125f + nk[r] * (-1e9f));
            sums[r] += p0 + p1;
            P[row][k0 + c]      = (bf16)p0;
            P[row][k0 + 16 + c] = (bf16)p1;
        }
    }

    // ---- Phase 2: row-sum reduce (c-group shuffle, then cross-wave via LDS)
    #pragma unroll
    for (int r = 0; r < 4; ++r) {
        float s = sums[r];
        s += __shfl_xor(s, 1); s += __shfl_xor(s, 2);
        s += __shfl_xor(s, 4); s += __shfl_xor(s, 8);
        if (c == 0) rs[wave][g * 4 + r] = s;
    }
    __syncthreads();
    if (tid < BQ) inv[tid] = 1.f / (rs[0][tid] + rs[1][tid] + rs[2][tid] + rs[3][tid]);
    __syncthreads();

    // ---- Phase 3: write normalized attention weights (coalesced f32, NONTEMPORAL)
    float* Wb = W + (size_t)bh * S * S + (size_t)q0 * S;
    #pragma unroll
    for (int it = 0; it < (BQ * S) / (256 * 8); ++it) {      // 16 iters
        const int flat = (it * 256 + tid) * 8;
        const int row  = flat >> 11;
        const int col  = flat & (S - 1);
        bf16x8 pv = *(const bf16x8*)&P[row][col];
        const float is = inv[row];
        float* dst = Wb + (size_t)row * S + col;
        f32x4 o0 = { (float)pv[0] * is, (float)pv[1] * is,
                     (float)pv[2] * is, (float)pv[3] * is };
        f32x4 o1 = { (float)pv[4] * is, (float)pv[5] * is,
                     (float)pv[6] * is, (float)pv[7] * is };
        __builtin_nontemporal_store(o0, (f32x4*)(dst));
        __builtin_nontemporal_store(o1, (f32x4*)(dst + 4));
    }

    // ---- Phase 4: O = P*V, k-split: wave owns keys [wave*512, wave*512+512),
    // computes partial O[16 q][64 d]; 32 V loads batched per 32-key chunk.
    f32x4 oacc[4] = {{0,0,0,0},{0,0,0,0},{0,0,0,0},{0,0,0,0}};
    const int kbase = wave * (S / 4);
    for (int kc = 0; kc < 16; ++kc) {
        const int kb = kbase + kc * 32;
        bf16x8 pa = *(const bf16x8*)&P[c][kb + g * 8];        // A: row=q(c)
        const float* vp = Vb + (size_t)(kb + g * 8) * DH + c;
        float vv0[8], vv1[8], vv2[8], vv3[8];
        #pragma unroll
        for (int j = 0; j < 8; ++j) {
            const float* vr = vp + (size_t)j * DH;
            vv0[j] = vr[0];  vv1[j] = vr[16];
            vv2[j] = vr[32]; vv3[j] = vr[48];
        }
        bf16x8 vb0, vb1, vb2, vb3;
        #pragma unroll
        for (int j = 0; j < 8; ++j) {
            vb0[j] = (bf16)vv0[j]; vb1[j] = (bf16)vv1[j];
            vb2[j] = (bf16)vv2[j]; vb3[j] = (bf16)vv3[j];
        }
        oacc[0] = __builtin_amdgcn_mfma_f32_16x16x32_bf16(pa, vb0, oacc[0], 0, 0, 0);
        oacc[1] = __builtin_amdgcn_mfma_f32_16x16x32_bf16(pa, vb1, oacc[1], 0, 0, 0);
        oacc[2] = __builtin_amdgcn_mfma_f32_16x16x32_bf16(pa, vb2, oacc[2], 0, 0, 0);
        oacc[3] = __builtin_amdgcn_mfma_f32_16x16x32_bf16(pa, vb3, oacc[3], 0, 0, 0);
    }

    // all waves done reading P -> alias opart over P's LDS
    __syncthreads();
    float* opart = (float*)&P[0][0];       // [4][16][64] f32 = 16 KB
    #pragma unroll
    for (int d4 = 0; d4 < 4; ++d4)
        #pragma unroll
        for (int r = 0; r < 4; ++r)
            opart[wave * 1024 + (g * 4 + r) * 64 + d4 * 16 + c] = oacc[d4][r];
    __syncthreads();

    // reduce partials + scale + write O (coalesced f32x4)
    {
        const int q = tid >> 4;            // 0..15
        const int d = (tid & 15) * 4;      // 0..60
        const float* p0 = opart + q * 64 + d;
        f32x4 o = *(const f32x4*)(p0)
                + *(const f32x4*)(p0 + 1024)
                + *(const f32x4*)(p0 + 2048)
                + *(const f32x4*)(p0 + 3072);
        const float is = inv[q];
        o.x *= is; o.y *= is; o.z *= is; o.w *= is;
        float* Ob = Out + ((size_t)bh * S + q0 + q) * DH + d;
        *(f32x4*)Ob = o;
    }
}

extern "C" void kernel_launch(void* const* d_in, const int* in_sizes, int n_in,
                              void* d_out, int out_size, void* d_ws, size_t ws_size,
                              hipStream_t stream) {
    const float* Q   = (const float*)d_in[0];
    const float* K   = (const float*)d_in[1];
    const float* V   = (const float*)d_in[2];
    const float* Msk = (const float*)d_in[3];

    float* Out = (float*)d_out;                       // [2,16,2048,64]
    float* W   = Out + (size_t)2 * 16 * 2048 * 64;    // [2,16,2048,2048]

    dim3 grid(32 * (S / BQ));
    dim3 block(256);
    hipLaunchKernelGGL(attn_fused, grid, block, 0, stream, Q, K, V, Msk, Out, W);
}